// Round 16
// baseline (467.268 us; speedup 1.0000x reference)
//
#include <hip/hip_runtime.h>
#include <math.h>

// Problem: B=128, P=128, D=128, N=4096, fp32 in/out.
// probs = softmax(10*tanh((A@K)/sqrt(128)) + mask) over n.
//
// R16: fp16x3 MFMA GEMM, tr_b16 operands, HALF-TILE LDS staging for occupancy.
//  K1: block = 128p x 128n C-tile, processed as two 64-col halves through a
//      34.8 KB LDS buffer (4 blocks/CU vs R15's 2). Masks for each half are
//      prefetched wholesale before the half's compute. e = exp(clip+mask) -> O;
//      row partials -> ws. (max-free softmax: |10tanh| <= 10 -> e <= 2.3e4)
//  K2: O *= 1/rowsum (32 partials per row).
constexpr int BB = 128;
constexpr int PP = 128;
constexpr int DD = 128;
constexpr int NN = 4096;
constexpr float kC = 10.0f;
constexpr float k2InvSqrtD = 0.1767766952966369f;   // 2/sqrt(128)

constexpr int NTHR = 512;
constexpr int TEL = 272;             // f16 elems per 16x16 tile incl pad (544 B)

typedef float f32x4 __attribute__((ext_vector_type(4)));
typedef _Float16 f16x4 __attribute__((ext_vector_type(4)));
typedef _Float16 f16x8 __attribute__((ext_vector_type(8)));

__device__ __forceinline__ void st_nt_f4(float* p, float4 s) {
    f32x4 v = {s.x, s.y, s.z, s.w};
    __builtin_nontemporal_store(v, (f32x4*)p);
}

// Hardware transpose read (HW-verified in R15): lane l (addr = tile + 8l)
// receives tile elems (l&15) + 16j + 64*(l>>4), i.e. row-major [16d][16n]:
// d_local = j + 4*(l>>4), n_local = l&15.
__device__ __forceinline__ f16x4 tr_read(unsigned addr) {
    f16x4 r;
    asm volatile("ds_read_b64_tr_b16 %0, %1" : "=v"(r) : "v"(addr));
    return r;
}

// z = 10*tanh(s/sqrt(128)) + m, via tanh(x) = 1 - 2/(e^{2x}+1)
__device__ __forceinline__ float clip1(float s, float m) {
    const float e2 = __expf(s * k2InvSqrtD);
    const float r = __builtin_amdgcn_rcpf(e2 + 1.0f);
    return fmaf(-2.0f * kC, r, kC) + m;
}

// ===================== Kernel 1: staged GEMM + clip + exp =====================
// Grid: 4096 = 128 b x 32 n-tiles. 512 thr = 8 waves; wave w owns rows w*16..+15.
// fp16x3: score = hh + hl + lh; k-packing d = kb*32 + 4g + (j&3) + 16*(j>>2)
// identical on A (regs) and B (tr reads) -> k-permutation errors cancel.
// C/D layout (HW-verified): col = lane&15, row = 4*(lane>>4) + reg.
// LDS per half: 8 dt x 4 ntile grid of 16x16 tiles (hi, lo), elem
// (d&15)*16 + (n&15), stride TEL -> b64 staging writes bank-spread, tr reads
// conflict-free (R15: SQ_LDS_BANK_CONFLICT = 0).
__global__ __launch_bounds__(NTHR, 4)    // pin 64-VGPR cap -> 4 blocks/CU
void score_kernel(const float* __restrict__ A,   // [B][P][D]
                  const float* __restrict__ K,   // [B][D][N]
                  const float* __restrict__ M,   // [B][P][N]
                  float* __restrict__ O,         // [B][P][N] <- exp(z)
                  float* __restrict__ ws) {      // [B*P][32] partial row sums
    __shared__ _Float16 Khi[32 * TEL];           // 17.4 KB
    __shared__ _Float16 Klo[32 * TEL];           // 17.4 KB

    const int l = blockIdx.x;
    const int b = l >> 5;
    const int ntb = l & 31;
    const int n_base = ntb * 128;

    const int tid = (int)threadIdx.x;
    const int lane = tid & 63;
    const int wid = tid >> 6;
    const int col = lane & 15;             // A row-in-frag / B col / C col
    const int g = lane >> 4;               // k-group / C row group
    const int kbase = 4 * g;

    // ---- A fragments (regs, whole kernel): 16 rows x 128 d per wave ----
    const float* Arow = A + (size_t)(b * PP + wid * 16 + col) * DD;
    f16x8 ah[4], al[4];
    #pragma unroll
    for (int kb = 0; kb < 4; ++kb) {
        #pragma unroll
        for (int j = 0; j < 8; ++j) {
            const int d = kb * 32 + kbase + (j & 3) + 16 * (j >> 2);
            const float x = Arow[d];
            const _Float16 h = (_Float16)x;
            ah[kb][j] = h;
            al[kb][j] = (_Float16)(x - (float)h);
        }
    }

    const size_t mrow0 = (size_t)(b * PP + wid * 16 + kbase) * NN + n_base + col;
    const unsigned khi0 = (unsigned)(uintptr_t)&Khi[0] + (unsigned)lane * 8u;
    const unsigned klo0 = (unsigned)(uintptr_t)&Klo[0] + (unsigned)lane * 8u;

    const float* Kg = K + (size_t)b * DD * NN + n_base;
    const int nl4 = (tid & 15) * 4;        // 4 consecutive n within the half
    const int d0 = tid >> 4;               // base d (0..31)
    const int ntile = nl4 >> 4;
    const int nin = nl4 & 12;

    float rsum[4] = {0.f, 0.f, 0.f, 0.f};

    #pragma unroll
    for (int half = 0; half < 2; ++half) {
        if (half) __syncthreads();         // all reads of prev half done

        // ---- stage this half's K (128 d x 64 n) hi/lo, b64 writes ----
        #pragma unroll
        for (int i = 0; i < 4; ++i) {
            const int d = d0 + 32 * i;
            const float4 v = *(const float4*)(Kg + (size_t)d * NN + half * 64 + nl4);
            const float xs[4] = {v.x, v.y, v.z, v.w};
            f16x4 h, lo;
            #pragma unroll
            for (int e = 0; e < 4; ++e) {
                const _Float16 hh = (_Float16)xs[e];
                h[e] = hh;
                lo[e] = (_Float16)(xs[e] - (float)hh);
            }
            const int el = ((d >> 4) * 4 + ntile) * TEL + (d & 15) * 16 + nin;
            *(f16x4*)&Khi[el] = h;
            *(f16x4*)&Klo[el] = lo;
        }

        // ---- prefetch ALL of this half's masks (latency hides under staging) ----
        float mv[16];
        #pragma unroll
        for (int nt2 = 0; nt2 < 4; ++nt2)
            #pragma unroll
            for (int j = 0; j < 4; ++j)
                mv[nt2 * 4 + j] =
                    M[mrow0 + (size_t)j * NN + half * 64 + nt2 * 16];

        __syncthreads();

        // ---- 4 n-subtiles of this half ----
        #pragma unroll
        for (int nt2 = 0; nt2 < 4; ++nt2) {
            f16x4 bh0[4], bh1[4], bl0[4], bl1[4];
            #pragma unroll
            for (int kb = 0; kb < 4; ++kb) {
                const unsigned t0 = (unsigned)(((2 * kb) * 4 + nt2) * 544);
                bh0[kb] = tr_read(khi0 + t0);
                bh1[kb] = tr_read(khi0 + t0 + 4u * 544u);
                bl0[kb] = tr_read(klo0 + t0);
                bl1[kb] = tr_read(klo0 + t0 + 4u * 544u);
            }
            asm volatile("s_waitcnt lgkmcnt(0)" ::: "memory");
            __builtin_amdgcn_sched_barrier(0);   // rule #18

            f32x4 acc = {0.f, 0.f, 0.f, 0.f};
            #pragma unroll
            for (int kb = 0; kb < 4; ++kb) {
                const f16x8 bh = __builtin_shufflevector(bh0[kb], bh1[kb], 0, 1, 2, 3, 4, 5, 6, 7);
                const f16x8 bl = __builtin_shufflevector(bl0[kb], bl1[kb], 0, 1, 2, 3, 4, 5, 6, 7);
                acc = __builtin_amdgcn_mfma_f32_16x16x32_f16(ah[kb], bh, acc, 0, 0, 0);
                acc = __builtin_amdgcn_mfma_f32_16x16x32_f16(ah[kb], bl, acc, 0, 0, 0);
                acc = __builtin_amdgcn_mfma_f32_16x16x32_f16(al[kb], bh, acc, 0, 0, 0);
            }

            // epilogue: e = exp(clip + mask); store; row partials
            #pragma unroll
            for (int j = 0; j < 4; ++j) {
                const size_t off = mrow0 + (size_t)j * NN + half * 64 + nt2 * 16;
                const float e = __expf(clip1(acc[j], mv[nt2 * 4 + j]));
                O[off] = e;                // cached: K2 re-reads via L2/L3
                rsum[j] += e;
            }
        }
    }

    // ---- reduce row partials across the 16 cols of each group -> ws ----
    #pragma unroll
    for (int j = 0; j < 4; ++j) {
        float s = rsum[j];
        s += __shfl_xor(s, 1);
        s += __shfl_xor(s, 2);
        s += __shfl_xor(s, 4);
        s += __shfl_xor(s, 8);
        rsum[j] = s;
    }
    if (col == 0) {
        #pragma unroll
        for (int j = 0; j < 4; ++j)
            ws[(size_t)(b * PP + wid * 16 + kbase + j) * 32 + ntb] = rsum[j];
    }
}

// ========================= Kernel 2: scale by 1/rowsum ========================
// Pure streaming: 2048 blocks x 256 thr; 32 threads/row, 32 f4/thread.
__global__ __launch_bounds__(256, 4)
void scale_kernel(float* __restrict__ O, const float* __restrict__ ws) {
    const int gtid = blockIdx.x * 256 + (int)threadIdx.x;
    const int row = gtid >> 5;
    const int seg = gtid & 31;

    const float* w = ws + (size_t)row * 32;
    float s = 0.f;
    #pragma unroll
    for (int i = 0; i < 8; ++i) {
        const float4 v = *(const float4*)(w + i * 4);
        s += (v.x + v.y) + (v.z + v.w);
    }
    const float inv = __builtin_amdgcn_rcpf(s);

    float4* R = (float4*)(O + (size_t)row * NN);
    #pragma unroll 8
    for (int i = 0; i < 32; ++i) {
        const int idx = i * 32 + seg;      // lanes consecutive -> coalesced
        float4 v = R[idx];
        v.x *= inv; v.y *= inv; v.z *= inv; v.w *= inv;
        st_nt_f4((float*)&R[idx], v);
    }
}

extern "C" void kernel_launch(void* const* d_in, const int* in_sizes, int n_in,
                              void* d_out, int out_size, void* d_ws, size_t ws_size,
                              hipStream_t stream) {
    const float* A = (const float*)d_in[0];   // mh_attn_out [128][128][128]
    const float* K = (const float*)d_in[1];   // single_head_key [128][128][4096]
    const float* M = (const float*)d_in[2];   // mask [128][128][4096]
    float* O = (float*)d_out;                 // probs [128][128][4096]
    float* ws = (float*)d_ws;                 // 16384 rows x 32 partials = 2 MB

    score_kernel<<<dim3(BB * 32), dim3(NTHR), 0, stream>>>(A, K, M, O, ws);
    scale_kernel<<<dim3(2048), dim3(256), 0, stream>>>(O, ws);
}

// Round 17
// 272.235 us; speedup vs baseline: 1.7164x; 1.7164x over previous
//
#include <hip/hip_runtime.h>
#include <math.h>

// Problem: B=128, P=128, D=128, N=4096, fp32 in/out.
// probs = softmax(10*tanh((A@K)/sqrt(128)) + mask) over n.
//
// R17: R15 kernel (proven 52 VGPR, 0 bank conflicts) with HALF-TILE LDS
// staging (34.8 KB -> 4 blocks/CU when VGPR <= 64) and NO forced VGPR cap
// (R16 lesson: pinning 64 on a ~85-reg structure spills catastrophically).
//  K1: e = exp(10*tanh(score/sqrt(128)) + mask) -> O; row partials -> ws.
//      (max-free softmax: |10tanh| <= 10 -> e <= 2.3e4, sum <= 9e7)
//  K2: O *= 1/rowsum (32 partials per row).
constexpr int BB = 128;
constexpr int PP = 128;
constexpr int DD = 128;
constexpr int NN = 4096;
constexpr float kC = 10.0f;
constexpr float k2InvSqrtD = 0.1767766952966369f;   // 2/sqrt(128)

constexpr int NTHR = 512;
constexpr int TEL = 272;             // f16 elems per 16x16 tile incl pad (544 B)

typedef float f32x4 __attribute__((ext_vector_type(4)));
typedef _Float16 f16x4 __attribute__((ext_vector_type(4)));
typedef _Float16 f16x8 __attribute__((ext_vector_type(8)));

__device__ __forceinline__ void st_nt_f4(float* p, float4 s) {
    f32x4 v = {s.x, s.y, s.z, s.w};
    __builtin_nontemporal_store(v, (f32x4*)p);
}

// Hardware transpose read (HW-verified R15): lane l (addr = tile + 8l)
// receives tile elems (l&15) + 16j + 64*(l>>4) of a row-major [16d][16n]
// tile: d_local = j + 4*(l>>4), n_local = l&15.
__device__ __forceinline__ f16x4 tr_read(unsigned addr) {
    f16x4 r;
    asm volatile("ds_read_b64_tr_b16 %0, %1" : "=v"(r) : "v"(addr));
    return r;
}

// z = 10*tanh(s/sqrt(128)) + m, via tanh(x) = 1 - 2/(e^{2x}+1)
__device__ __forceinline__ float clip1(float s, float m) {
    const float e2 = __expf(s * k2InvSqrtD);
    const float r = __builtin_amdgcn_rcpf(e2 + 1.0f);
    return fmaf(-2.0f * kC, r, kC) + m;
}

// ===================== Kernel 1: staged GEMM + clip + exp =====================
// Grid: 4096 = 128 b x 32 n-tiles. 512 thr = 8 waves; wave w owns rows w*16..+15.
// fp16x3: score = hh + hl + lh; k-packing d = kb*32 + 4g + (j&3) + 16*(j>>2)
// identical on A (regs) and B (tr reads) -> k-permutation errors cancel.
// C/D layout (HW-verified): col = lane&15, row = 4*(lane>>4) + reg.
// LDS holds HALF the K tile (128d x 64n) as 8x4 grid of 16x16 hi/lo tiles;
// elem (d&15)*16 + (n&15), stride TEL. b64 staging writes bank-spread;
// tr reads conflict-free (R15: SQ_LDS_BANK_CONFLICT = 0).
__global__ __launch_bounds__(NTHR, 2)    // cap 128; measured use ~52-64
void score_kernel(const float* __restrict__ A,   // [B][P][D]
                  const float* __restrict__ K,   // [B][D][N]
                  const float* __restrict__ M,   // [B][P][N]
                  float* __restrict__ O,         // [B][P][N] <- exp(z)
                  float* __restrict__ ws) {      // [B*P][32] partial row sums
    __shared__ _Float16 Khi[32 * TEL];           // 17.4 KB
    __shared__ _Float16 Klo[32 * TEL];           // 17.4 KB

    const int l = blockIdx.x;
    const int b = l >> 5;
    const int ntb = l & 31;
    const int n_base = ntb * 128;

    const int tid = (int)threadIdx.x;
    const int lane = tid & 63;
    const int wid = tid >> 6;
    const int col = lane & 15;             // A row-in-frag / B col / C col
    const int g = lane >> 4;               // k-group / C row group
    const int kbase = 4 * g;

    // ---- A fragments (regs, whole kernel): 16 rows x 128 d per wave ----
    const float* Arow = A + (size_t)(b * PP + wid * 16 + col) * DD;
    f16x8 ah[4], al[4];
    #pragma unroll
    for (int kb = 0; kb < 4; ++kb) {
        #pragma unroll
        for (int j = 0; j < 8; ++j) {
            const int d = kb * 32 + kbase + (j & 3) + 16 * (j >> 2);
            const float x = Arow[d];
            const _Float16 h = (_Float16)x;
            ah[kb][j] = h;
            al[kb][j] = (_Float16)(x - (float)h);
        }
    }

    const size_t mrow0 = (size_t)(b * PP + wid * 16 + kbase) * NN + n_base + col;
    const unsigned khi0 = (unsigned)(uintptr_t)&Khi[0] + (unsigned)lane * 8u;
    const unsigned klo0 = (unsigned)(uintptr_t)&Klo[0] + (unsigned)lane * 8u;

    const float* Kg = K + (size_t)b * DD * NN + n_base;
    const int nl4 = (tid & 15) * 4;        // 4 consecutive n within the half
    const int d0 = tid >> 4;               // base d (0..31)
    const int ntile = nl4 >> 4;
    const int nin = nl4 & 12;

    float rsum[4] = {0.f, 0.f, 0.f, 0.f};

    // rolling per-nt mask prefetch (register-cheap, proven in R15)
    float mv[4];
    #pragma unroll
    for (int j = 0; j < 4; ++j) mv[j] = M[mrow0 + (size_t)j * NN];

    #pragma unroll
    for (int half = 0; half < 2; ++half) {
        if (half) __syncthreads();         // all reads of prev half done

        // ---- stage this half's K (128 d x 64 n) hi/lo, b64 writes ----
        #pragma unroll
        for (int i = 0; i < 4; ++i) {
            const int d = d0 + 32 * i;
            const float4 v = *(const float4*)(Kg + (size_t)d * NN + half * 64 + nl4);
            const float xs[4] = {v.x, v.y, v.z, v.w};
            f16x4 h, lo;
            #pragma unroll
            for (int e = 0; e < 4; ++e) {
                const _Float16 hh = (_Float16)xs[e];
                h[e] = hh;
                lo[e] = (_Float16)(xs[e] - (float)hh);
            }
            const int el = ((d >> 4) * 4 + ntile) * TEL + (d & 15) * 16 + nin;
            *(f16x4*)&Khi[el] = h;
            *(f16x4*)&Klo[el] = lo;
        }
        __syncthreads();

        // ---- 4 n-subtiles of this half ----
        #pragma unroll
        for (int nt2 = 0; nt2 < 4; ++nt2) {
            const int nt = half * 4 + nt2;         // global n-subtile 0..7

            // prefetch next subtile's mask (crosses the half boundary too)
            float mvn[4] = {0.f, 0.f, 0.f, 0.f};
            if (nt < 7) {
                #pragma unroll
                for (int j = 0; j < 4; ++j)
                    mvn[j] = M[mrow0 + (size_t)j * NN + (nt + 1) * 16];
            }

            f16x4 bh0[4], bh1[4], bl0[4], bl1[4];
            #pragma unroll
            for (int kb = 0; kb < 4; ++kb) {
                const unsigned t0 = (unsigned)(((2 * kb) * 4 + nt2) * 544);
                bh0[kb] = tr_read(khi0 + t0);
                bh1[kb] = tr_read(khi0 + t0 + 4u * 544u);
                bl0[kb] = tr_read(klo0 + t0);
                bl1[kb] = tr_read(klo0 + t0 + 4u * 544u);
            }
            asm volatile("s_waitcnt lgkmcnt(0)" ::: "memory");
            __builtin_amdgcn_sched_barrier(0);     // rule #18

            f32x4 acc = {0.f, 0.f, 0.f, 0.f};
            #pragma unroll
            for (int kb = 0; kb < 4; ++kb) {
                const f16x8 bh = __builtin_shufflevector(bh0[kb], bh1[kb], 0, 1, 2, 3, 4, 5, 6, 7);
                const f16x8 bl = __builtin_shufflevector(bl0[kb], bl1[kb], 0, 1, 2, 3, 4, 5, 6, 7);
                acc = __builtin_amdgcn_mfma_f32_16x16x32_f16(ah[kb], bh, acc, 0, 0, 0);
                acc = __builtin_amdgcn_mfma_f32_16x16x32_f16(ah[kb], bl, acc, 0, 0, 0);
                acc = __builtin_amdgcn_mfma_f32_16x16x32_f16(al[kb], bh, acc, 0, 0, 0);
            }

            // epilogue: e = exp(clip + mask); store; row partials
            #pragma unroll
            for (int j = 0; j < 4; ++j) {
                const size_t off = mrow0 + (size_t)j * NN + nt * 16;
                const float e = __expf(clip1(acc[j], mv[j]));
                O[off] = e;                // cached: K2 re-reads via L2/L3
                rsum[j] += e;
            }
            #pragma unroll
            for (int j = 0; j < 4; ++j) mv[j] = mvn[j];
        }
    }

    // ---- reduce row partials across the 16 cols of each group -> ws ----
    #pragma unroll
    for (int j = 0; j < 4; ++j) {
        float s = rsum[j];
        s += __shfl_xor(s, 1);
        s += __shfl_xor(s, 2);
        s += __shfl_xor(s, 4);
        s += __shfl_xor(s, 8);
        rsum[j] = s;
    }
    if (col == 0) {
        #pragma unroll
        for (int j = 0; j < 4; ++j)
            ws[(size_t)(b * PP + wid * 16 + kbase + j) * 32 + ntb] = rsum[j];
    }
}

// ========================= Kernel 2: scale by 1/rowsum ========================
// Pure streaming: 2048 blocks x 256 thr; 32 threads/row, 32 f4/thread.
__global__ __launch_bounds__(256, 4)
void scale_kernel(float* __restrict__ O, const float* __restrict__ ws) {
    const int gtid = blockIdx.x * 256 + (int)threadIdx.x;
    const int row = gtid >> 5;
    const int seg = gtid & 31;

    const float* w = ws + (size_t)row * 32;
    float s = 0.f;
    #pragma unroll
    for (int i = 0; i < 8; ++i) {
        const float4 v = *(const float4*)(w + i * 4);
        s += (v.x + v.y) + (v.z + v.w);
    }
    const float inv = __builtin_amdgcn_rcpf(s);

    float4* R = (float4*)(O + (size_t)row * NN);
    #pragma unroll 8
    for (int i = 0; i < 32; ++i) {
        const int idx = i * 32 + seg;      // lanes consecutive -> coalesced
        float4 v = R[idx];
        v.x *= inv; v.y *= inv; v.z *= inv; v.w *= inv;
        st_nt_f4((float*)&R[idx], v);
    }
}

extern "C" void kernel_launch(void* const* d_in, const int* in_sizes, int n_in,
                              void* d_out, int out_size, void* d_ws, size_t ws_size,
                              hipStream_t stream) {
    const float* A = (const float*)d_in[0];   // mh_attn_out [128][128][128]
    const float* K = (const float*)d_in[1];   // single_head_key [128][128][4096]
    const float* M = (const float*)d_in[2];   // mask [128][128][4096]
    float* O = (float*)d_out;                 // probs [128][128][4096]
    float* ws = (float*)d_ws;                 // 16384 rows x 32 partials = 2 MB

    score_kernel<<<dim3(BB * 32), dim3(NTHR), 0, stream>>>(A, K, M, O, ws);
    scale_kernel<<<dim3(2048), dim3(256), 0, stream>>>(O, ws);
}

// Round 18
// 268.744 us; speedup vs baseline: 1.7387x; 1.0130x over previous
//
#include <hip/hip_runtime.h>
#include <math.h>

// Problem: B=128, P=128, D=128, N=4096, fp32 in/out.
// probs = softmax(10*tanh((A@K)/sqrt(128)) + mask) over n.
//
// R18: R17 + T14 async-stage discipline: each half's compute region is
// LOAD-FREE (masks preloaded to regs; next half's K issued early into regs,
// split+written to LDS late). Kills the per-nt store->load vmcnt serialization.
//  K1: e = exp(10*tanh(score/sqrt(128)) + mask) -> O; row partials -> ws.
//      (max-free softmax: |10tanh| <= 10 -> e <= 2.3e4, sum <= 9e7)
//  K2: O *= 1/rowsum (32 partials per row).
constexpr int BB = 128;
constexpr int PP = 128;
constexpr int DD = 128;
constexpr int NN = 4096;
constexpr float kC = 10.0f;
constexpr float k2InvSqrtD = 0.1767766952966369f;   // 2/sqrt(128)

constexpr int NTHR = 512;
constexpr int TEL = 272;             // f16 elems per 16x16 tile incl pad (544 B)

typedef float f32x4 __attribute__((ext_vector_type(4)));
typedef _Float16 f16x4 __attribute__((ext_vector_type(4)));
typedef _Float16 f16x8 __attribute__((ext_vector_type(8)));

__device__ __forceinline__ void st_nt_f4(float* p, float4 s) {
    f32x4 v = {s.x, s.y, s.z, s.w};
    __builtin_nontemporal_store(v, (f32x4*)p);
}

// Hardware transpose read (HW-verified R15): lane l (addr = tile + 8l)
// receives tile elems (l&15) + 16j + 64*(l>>4) of a row-major [16d][16n]
// tile: d_local = j + 4*(l>>4), n_local = l&15.
__device__ __forceinline__ f16x4 tr_read(unsigned addr) {
    f16x4 r;
    asm volatile("ds_read_b64_tr_b16 %0, %1" : "=v"(r) : "v"(addr));
    return r;
}

// z = 10*tanh(s/sqrt(128)) + m, via tanh(x) = 1 - 2/(e^{2x}+1)
__device__ __forceinline__ float clip1(float s, float m) {
    const float e2 = __expf(s * k2InvSqrtD);
    const float r = __builtin_amdgcn_rcpf(e2 + 1.0f);
    return fmaf(-2.0f * kC, r, kC) + m;
}

// ===================== Kernel 1: staged GEMM + clip + exp =====================
// Grid: 4096 = 128 b x 32 n-tiles. 512 thr = 8 waves; wave w owns rows w*16..+15.
// fp16x3: score = hh + hl + lh; k-packing d = kb*32 + 4g + (j&3) + 16*(j>>2)
// identical on A (regs) and B (tr reads) -> k-permutation errors cancel.
// C/D layout (HW-verified): col = lane&15, row = 4*(lane>>4) + reg.
// LDS holds HALF the K tile (128d x 64n) as 8x4 grid of 16x16 hi/lo tiles;
// tr reads conflict-free (R15/R17: SQ_LDS_BANK_CONFLICT = 0).
__global__ __launch_bounds__(NTHR, 2)    // cap 128; design ~115 live
void score_kernel(const float* __restrict__ A,   // [B][P][D]
                  const float* __restrict__ K,   // [B][D][N]
                  const float* __restrict__ M,   // [B][P][N]
                  float* __restrict__ O,         // [B][P][N] <- exp(z)
                  float* __restrict__ ws) {      // [B*P][32] partial row sums
    __shared__ _Float16 Khi[32 * TEL];           // 17.4 KB
    __shared__ _Float16 Klo[32 * TEL];           // 17.4 KB

    const int l = blockIdx.x;
    const int b = l >> 5;
    const int ntb = l & 31;
    const int n_base = ntb * 128;

    const int tid = (int)threadIdx.x;
    const int lane = tid & 63;
    const int wid = tid >> 6;
    const int col = lane & 15;             // A row-in-frag / B col / C col
    const int g = lane >> 4;               // k-group / C row group
    const int kbase = 4 * g;

    // ---- A fragments (regs, whole kernel): 16 rows x 128 d per wave ----
    const float* Arow = A + (size_t)(b * PP + wid * 16 + col) * DD;
    f16x8 ah[4], al[4];
    #pragma unroll
    for (int kb = 0; kb < 4; ++kb) {
        #pragma unroll
        for (int j = 0; j < 8; ++j) {
            const int d = kb * 32 + kbase + (j & 3) + 16 * (j >> 2);
            const float x = Arow[d];
            const _Float16 h = (_Float16)x;
            ah[kb][j] = h;
            al[kb][j] = (_Float16)(x - (float)h);
        }
    }

    const size_t mrow0 = (size_t)(b * PP + wid * 16 + kbase) * NN + n_base + col;
    const unsigned khi0 = (unsigned)(uintptr_t)&Khi[0] + (unsigned)lane * 8u;
    const unsigned klo0 = (unsigned)(uintptr_t)&Klo[0] + (unsigned)lane * 8u;

    const float* Kg = K + (size_t)b * DD * NN + n_base;
    const int nl4 = (tid & 15) * 4;        // 4 consecutive n within the half
    const int d0 = tid >> 4;               // base d (0..31)
    const int ntile = nl4 >> 4;
    const int nin = nl4 & 12;
    const int el0 = ((d0 >> 4) * 4 + ntile) * TEL + (d0 & 15) * 16 + nin;

    float rsum[4] = {0.f, 0.f, 0.f, 0.f};

    // ---- prologue: load half0 K -> regs, split -> LDS; issue half1 K loads;
    //      preload half0 masks; barrier. ----
    float4 kreg[4];
    #pragma unroll
    for (int i = 0; i < 4; ++i)
        kreg[i] = *(const float4*)(Kg + (size_t)(d0 + 32 * i) * NN + nl4);
    #pragma unroll
    for (int i = 0; i < 4; ++i) {
        const float xs[4] = {kreg[i].x, kreg[i].y, kreg[i].z, kreg[i].w};
        f16x4 h, lo;
        #pragma unroll
        for (int e = 0; e < 4; ++e) {
            const _Float16 hh = (_Float16)xs[e];
            h[e] = hh;
            lo[e] = (_Float16)(xs[e] - (float)hh);
        }
        const int el = el0 + i * 8 * TEL;    // d-tile advances by 2 per i
        *(f16x4*)&Khi[el] = h;
        *(f16x4*)&Klo[el] = lo;
    }
    #pragma unroll
    for (int i = 0; i < 4; ++i)              // half1 K: issue EARLY (T14)
        kreg[i] = *(const float4*)(Kg + (size_t)(d0 + 32 * i) * NN + 64 + nl4);

    float mv[16];                            // half0 masks
    #pragma unroll
    for (int nt2 = 0; nt2 < 4; ++nt2)
        #pragma unroll
        for (int j = 0; j < 4; ++j)
            mv[nt2 * 4 + j] = M[mrow0 + (size_t)j * NN + nt2 * 16];
    __syncthreads();

    #pragma unroll
    for (int half = 0; half < 2; ++half) {
        // ---- compute this half: LOAD-FREE region (ds + MFMA + VALU + stores) ----
        #pragma unroll
        for (int nt2 = 0; nt2 < 4; ++nt2) {
            const int nt = half * 4 + nt2;

            f16x4 bh0[4], bh1[4], bl0[4], bl1[4];
            #pragma unroll
            for (int kb = 0; kb < 4; ++kb) {
                const unsigned t0 = (unsigned)(((2 * kb) * 4 + nt2) * 544);
                bh0[kb] = tr_read(khi0 + t0);
                bh1[kb] = tr_read(khi0 + t0 + 4u * 544u);
                bl0[kb] = tr_read(klo0 + t0);
                bl1[kb] = tr_read(klo0 + t0 + 4u * 544u);
            }
            asm volatile("s_waitcnt lgkmcnt(0)" ::: "memory");
            __builtin_amdgcn_sched_barrier(0);     // rule #18

            f32x4 acc = {0.f, 0.f, 0.f, 0.f};
            #pragma unroll
            for (int kb = 0; kb < 4; ++kb) {
                const f16x8 bh = __builtin_shufflevector(bh0[kb], bh1[kb], 0, 1, 2, 3, 4, 5, 6, 7);
                const f16x8 bl = __builtin_shufflevector(bl0[kb], bl1[kb], 0, 1, 2, 3, 4, 5, 6, 7);
                acc = __builtin_amdgcn_mfma_f32_16x16x32_f16(ah[kb], bh, acc, 0, 0, 0);
                acc = __builtin_amdgcn_mfma_f32_16x16x32_f16(ah[kb], bl, acc, 0, 0, 0);
                acc = __builtin_amdgcn_mfma_f32_16x16x32_f16(al[kb], bh, acc, 0, 0, 0);
            }

            // epilogue: e = exp(clip + mask); store (fire-and-forget); partials
            #pragma unroll
            for (int j = 0; j < 4; ++j) {
                const size_t off = mrow0 + (size_t)j * NN + nt * 16;
                const float e = __expf(clip1(acc[j], mv[nt2 * 4 + j]));
                O[off] = e;                // cached: K2 re-reads via L2/L3
                rsum[j] += e;
            }
        }

        if (half == 0) {
            __syncthreads();               // all tr reads of half0 done
            // split half1 K (vmcnt wait on kreg) -> LDS
            #pragma unroll
            for (int i = 0; i < 4; ++i) {
                const float xs[4] = {kreg[i].x, kreg[i].y, kreg[i].z, kreg[i].w};
                f16x4 h, lo;
                #pragma unroll
                for (int e = 0; e < 4; ++e) {
                    const _Float16 hh = (_Float16)xs[e];
                    h[e] = hh;
                    lo[e] = (_Float16)(xs[e] - (float)hh);
                }
                const int el = el0 + i * 8 * TEL;
                *(f16x4*)&Khi[el] = h;
                *(f16x4*)&Klo[el] = lo;
            }
            // preload half1 masks (latency hidden under barrier + first nt)
            #pragma unroll
            for (int nt2 = 0; nt2 < 4; ++nt2)
                #pragma unroll
                for (int j = 0; j < 4; ++j)
                    mv[nt2 * 4 + j] = M[mrow0 + (size_t)j * NN + 64 + nt2 * 16];
            __syncthreads();
        }
    }

    // ---- reduce row partials across the 16 cols of each group -> ws ----
    #pragma unroll
    for (int j = 0; j < 4; ++j) {
        float s = rsum[j];
        s += __shfl_xor(s, 1);
        s += __shfl_xor(s, 2);
        s += __shfl_xor(s, 4);
        s += __shfl_xor(s, 8);
        rsum[j] = s;
    }
    if (col == 0) {
        #pragma unroll
        for (int j = 0; j < 4; ++j)
            ws[(size_t)(b * PP + wid * 16 + kbase + j) * 32 + ntb] = rsum[j];
    }
}

// ========================= Kernel 2: scale by 1/rowsum ========================
// Pure streaming: 2048 blocks x 256 thr; 32 threads/row, 32 f4/thread.
__global__ __launch_bounds__(256, 4)
void scale_kernel(float* __restrict__ O, const float* __restrict__ ws) {
    const int gtid = blockIdx.x * 256 + (int)threadIdx.x;
    const int row = gtid >> 5;
    const int seg = gtid & 31;

    const float* w = ws + (size_t)row * 32;
    float s = 0.f;
    #pragma unroll
    for (int i = 0; i < 8; ++i) {
        const float4 v = *(const float4*)(w + i * 4);
        s += (v.x + v.y) + (v.z + v.w);
    }
    const float inv = __builtin_amdgcn_rcpf(s);

    float4* R = (float4*)(O + (size_t)row * NN);
    #pragma unroll 8
    for (int i = 0; i < 32; ++i) {
        const int idx = i * 32 + seg;      // lanes consecutive -> coalesced
        float4 v = R[idx];
        v.x *= inv; v.y *= inv; v.z *= inv; v.w *= inv;
        st_nt_f4((float*)&R[idx], v);
    }
}

extern "C" void kernel_launch(void* const* d_in, const int* in_sizes, int n_in,
                              void* d_out, int out_size, void* d_ws, size_t ws_size,
                              hipStream_t stream) {
    const float* A = (const float*)d_in[0];   // mh_attn_out [128][128][128]
    const float* K = (const float*)d_in[1];   // single_head_key [128][128][4096]
    const float* M = (const float*)d_in[2];   // mask [128][128][4096]
    float* O = (float*)d_out;                 // probs [128][128][4096]
    float* ws = (float*)d_ws;                 // 16384 rows x 32 partials = 2 MB

    score_kernel<<<dim3(BB * 32), dim3(NTHR), 0, stream>>>(A, K, M, O, ws);
    scale_kernel<<<dim3(2048), dim3(256), 0, stream>>>(O, ws);
}